// Round 8
// baseline (308.288 us; speedup 1.0000x reference)
//
#include <hip/hip_runtime.h>
#include <hip/hip_cooperative_groups.h>
#include <stdint.h>

namespace cg = cooperative_groups;

#define NPTS 21760
#define NCLS 80
#define NSC (NPTS * NCLS)          // 1,740,800 flat scores
#define NSC4 (NSC / 4)             // 435,200 float4s in the score region
#define PRE_K 4096
#define NMSMAX 100
#define CONF 0.35f
#define IOUT 0.6f
#define INSZ 1024.0f
#define CAND_CAP 8192
#define B_LO 16051u                 // __float_as_uint(0.35f) >> 16
#define B_HI 16224u                 // __float_as_uint(0.875f) >> 16 — hist floor
#define HB2 33                      // buckets 16224..16256 (sg==1.0f lands in 16256)
#define GRID 256                    // cooperative grid: 1 block/CU

// ---- workspace layout (bytes) ----
#define OFF_BBOX  0                                 // 21760 * float4 = 348,160
#define OFF_PART  (OFF_BBOX + NPTS * 16)            // 256 * 33 u32 partial hists
#define OFF_SCAL  (OFF_PART + GRID * HB2 * 4)       // [1]=cand count
#define OFF_CAND  (OFF_SCAL + 64)                   // 8192 u64
#define OFF_SORT  (OFF_CAND + CAND_CAP * 8)         // 4096 u64
// total ~470 KB

typedef unsigned long long u64;

__device__ inline bool iou_gt(const float* a, const float* b) {
    float aa = (a[2] - a[0]) * (a[3] - a[1]);
    float ab = (b[2] - b[0]) * (b[3] - b[1]);
    float lx = fmaxf(a[0], b[0]), ly = fmaxf(a[1], b[1]);
    float rx = fminf(a[2], b[2]), ry = fminf(a[3], b[3]);
    float w = fmaxf(rx - lx, 0.f), h = fmaxf(ry - ly, 0.f);
    float inter = w * h;
    return inter / (aa + ab - inter + 1e-6f) > IOUT;
}

__global__ __launch_bounds__(256) void k_all(const float* __restrict__ preds,
                                             float* __restrict__ bbox,
                                             uint32_t* __restrict__ part,
                                             uint32_t* __restrict__ scal,
                                             u64* __restrict__ cand,
                                             u64* __restrict__ sorted,
                                             const float* __restrict__ warp,
                                             const int* __restrict__ hgt,
                                             const int* __restrict__ wid,
                                             float* __restrict__ out) {
    cg::grid_group grid = cg::this_grid();
    __shared__ uint32_t lh[HB2];
    __shared__ uint32_t cut_s;
    __shared__ u64 buf[4096];
    __shared__ uint32_t lcnt, lbase;
    __shared__ u64 tile[256];
    // NMS state
    __shared__ float s_cbox[64][4];
    __shared__ float s_cval[64];
    __shared__ int   s_cidx[64];
    __shared__ u64   s_intra[64];
    __shared__ int   s_sup[64];
    __shared__ int   s_kidx[NMSMAX];
    __shared__ float s_kval[NMSMAX];
    __shared__ float s_kbox[NMSMAX][4];
    __shared__ int   s_kc, s_done;

    const int t = threadIdx.x;
    const int blk = blockIdx.x;

    // ================= Phase A: hist partials + bbox decode + init =================
    if (t < HB2) lh[t] = 0;
    __syncthreads();

    // high-score histogram over the score region (grid-stride float4)
    for (int g = blk * 256 + t; g < NSC4; g += GRID * 256) {
        int a = g / 20, c4 = g - a * 20;
        float4 v = *(const float4*)(preds + (size_t)a * 112 + c4 * 4);
        float vv[4] = { v.x, v.y, v.z, v.w };
        #pragma unroll
        for (int e = 0; e < 4; ++e) {
            float sg = 1.0f / (1.0f + expf(-vv[e]));
            uint32_t b = __float_as_uint(sg) >> 16;
            if (b >= B_HI) atomicAdd(&lh[b - B_HI], 1u);
        }
    }
    __syncthreads();
    if (t < HB2) part[blk * HB2 + t] = lh[t];     // plain store: no pre-zero needed
    if (blk == 0 && t == 0) scal[1] = 0;
    if (t < 16) sorted[blk * 16 + t] = ~0ull;     // prefill padding keys

    // bbox decode: 4 threads per anchor, shuffle-assemble (grid-stride)
    for (int idx = blk * 256 + t; idx < NPTS * 4; idx += GRID * 256) {
        int n = idx >> 2, k = idx & 3;
        int s, fs, local;
        if (n < 16384)      { s = 8;  fs = 128; local = n; }
        else if (n < 20480) { s = 16; fs = 64;  local = n - 16384; }
        else if (n < 21504) { s = 32; fs = 32;  local = n - 20480; }
        else                { s = 64; fs = 16;  local = n - 21504; }
        const float4* rp = (const float4*)(preds + (size_t)n * 112 + 80 + k * 8);
        float4 r0 = rp[0], r1 = rp[1];
        float r[8] = { r0.x, r0.y, r0.z, r0.w, r1.x, r1.y, r1.z, r1.w };
        float m = r[0];
        #pragma unroll
        for (int j = 1; j < 8; ++j) m = fmaxf(m, r[j]);
        float sum = 0.f, dot = 0.f;
        #pragma unroll
        for (int j = 0; j < 8; ++j) { float e = expf(r[j] - m); sum += e; dot += e * (float)j; }
        float dv = (dot / sum) * (float)s;
        int lane = t & 63, base = lane & ~3;
        float d0 = __shfl(dv, base + 0);
        float d1 = __shfl(dv, base + 1);
        float d2 = __shfl(dv, base + 2);
        float d3 = __shfl(dv, base + 3);
        if (k == 0) {
            float cx = (float)((local % fs) * s);
            float cy = (float)((local / fs) * s);
            float4 bb;
            bb.x = fminf(fmaxf(cx - d0, 0.f), INSZ);
            bb.y = fminf(fmaxf(cy - d1, 0.f), INSZ);
            bb.z = fminf(fmaxf(cx + d2, 0.f), INSZ);
            bb.w = fminf(fmaxf(cy + d3, 0.f), INSZ);
            ((float4*)bbox)[n] = bb;
        }
    }
    grid.sync();

    // ================= Phase B: cutoff + compact =================
    if (t < HB2) lh[t] = 0;
    if (t == 0) lcnt = 0;
    __syncthreads();
    {   // every block redundantly sums the 256x33 partials (L2-hot, ~1 us)
        const uint32_t* row = part + t * HB2;
        #pragma unroll
        for (int k = 0; k < HB2; ++k) {
            uint32_t v = row[k];
            if (v) atomicAdd(&lh[k], v);
        }
    }
    __syncthreads();
    if (t == 0) {
        uint32_t suf = 0, c = B_LO;               // fallback: take all > CONF
        for (int b = HB2 - 1; b >= 0; --b) {
            suf += lh[b];
            if (suf >= PRE_K) { c = B_HI + (uint32_t)b; break; }
        }
        cut_s = c;
    }
    __syncthreads();
    uint32_t cut = cut_s;

    for (int g = blk * 256 + t; g < NSC4; g += GRID * 256) {
        int a = g / 20, c4 = g - a * 20;
        float4 v = *(const float4*)(preds + (size_t)a * 112 + c4 * 4);
        float vv[4] = { v.x, v.y, v.z, v.w };
        #pragma unroll
        for (int e = 0; e < 4; ++e) {
            float sg = 1.0f / (1.0f + expf(-vv[e]));   // byte-identical to hist phase
            uint32_t bits = __float_as_uint(sg);
            if ((bits >> 16) >= cut) {
                uint32_t p = atomicAdd(&lcnt, 1u);
                if (p < 4096u) buf[p] = ((u64)(~bits) << 32) | (u64)(uint32_t)(a * 80 + c4 * 4 + e);
            }
        }
    }
    __syncthreads();
    uint32_t cnt = lcnt < 4096u ? lcnt : 4096u;
    if (t == 0) lbase = atomicAdd(&scal[1], cnt);
    __syncthreads();
    {
        uint32_t b0 = lbase;
        for (uint32_t k = t; k < cnt; k += 256) {
            uint32_t pos = b0 + k;
            if (pos < CAND_CAP) cand[pos] = buf[k];
        }
    }
    grid.sync();

    // ================= Phase C: rank-by-count (8 threads / candidate) =================
    {
        uint32_t M = scal[1];
        if (M > CAND_CAP) M = CAND_CAP;
        int c = t >> 3;                 // candidate-in-block 0..31
        int s = t & 7;                  // j-subgroup 0..7
        int i = blk * 32 + c;           // 256 blocks * 32 = 8192
        u64 my = (i < (int)M) ? cand[i] : ~0ull;
        int rank = 0;
        uint32_t ntiles = (M + 255u) >> 8;
        for (uint32_t tb = 0; tb < ntiles; ++tb) {
            uint32_t j = tb * 256 + t;
            tile[t] = (j < M) ? cand[j] : ~0ull;
            __syncthreads();
            #pragma unroll 8
            for (int it = 0; it < 32; ++it)
                rank += (int)(tile[it * 8 + s] < my);
            __syncthreads();
        }
        rank += __shfl_down(rank, 4, 8);
        rank += __shfl_down(rank, 2, 8);
        rank += __shfl_down(rank, 1, 8);
        if (s == 0 && i < (int)M && rank < PRE_K) sorted[rank] = my;
    }
    __threadfence();
    grid.sync();

    // ================= Phase D: NMS + epilogue (block 0 only) =================
    if (blk != 0) return;
    if (t == 0) { s_kc = 0; s_done = 0; }
    __syncthreads();

    for (int c = 0; c < PRE_K / 64; ++c) {
        if (t < 64) {
            u64 sk = sorted[c * 64 + t];
            uint32_t fidx = (uint32_t)sk;
            float val = __uint_as_float(~(uint32_t)(sk >> 32));
            uint32_t bi = fidx / NCLS;
            if (bi >= NPTS) bi = NPTS - 1;       // padding keys: clamp (invalid anyway)
            int cls = (int)fidx - (int)bi * NCLS;
            float off = (float)cls * (INSZ + 1.0f);
            float4 bb = ((const float4*)bbox)[bi];
            s_cbox[t][0] = bb.x + off; s_cbox[t][1] = bb.y + off;
            s_cbox[t][2] = bb.z + off; s_cbox[t][3] = bb.w + off;
            s_cval[t] = val; s_cidx[t] = (int)fidx; s_sup[t] = 0;
        }
        __syncthreads();
        int kc_snap = s_kc;
        {   // suppression by previously-kept boxes (256 threads = 64 cands x 4 groups)
            int j = t & 63, g = t >> 6;
            bool sup = false;
            for (int k = g; k < kc_snap; k += 4)
                sup |= iou_gt(s_cbox[j], s_kbox[k]);
            if (sup) atomicOr(&s_sup[j], 1);
        }
        if (t < 64) {  // intra-chunk upper-triangular mask
            u64 rowm = 0;
            for (int j2 = t + 1; j2 < 64; ++j2)
                if (iou_gt(s_cbox[t], s_cbox[j2])) rowm |= 1ull << j2;
            s_intra[t] = rowm;
        }
        __syncthreads();
        if (t < 64) {  // serial resolve, wave 0 only, wave-uniform control
            u64 intrarow = s_intra[t];
            u64 supw = __ballot(s_sup[t] != 0);
            u64 valw = __ballot(s_cval[t] > CONF);
            u64 cur = valw & ~supw;
            int kc = kc_snap;
            for (int b = 0; b < 64; ++b) {
                if (kc >= NMSMAX) break;
                if ((cur >> b) & 1ull) {
                    if (t == 0) { s_kidx[kc] = s_cidx[b]; s_kval[kc] = s_cval[b]; }
                    if (t < 4) s_kbox[kc][t] = s_cbox[b][t];
                    kc++;
                    cur &= ~__shfl(intrarow, b);
                }
            }
            if (t == 0) { s_kc = kc; s_done = (kc >= NMSMAX) ? 1 : 0; }
        }
        __syncthreads();
        if (s_done) break;
    }
    __syncthreads();

    // epilogue: inverse warp, clip, write dets (100x5) then labels (100)
    if (t < NMSMAX) {
        float a = warp[0], b = warp[1], cc = warp[2];
        float d = warp[3], e = warp[4], f = warp[5];
        float g = warp[6], h = warp[7], i9 = warp[8];
        float det = a * (e * i9 - f * h) - b * (d * i9 - f * g) + cc * (d * h - e * g);
        float i00 = (e * i9 - f * h) / det, i01 = (cc * h - b * i9) / det, i02 = (b * f - cc * e) / det;
        float i10 = (f * g - d * i9) / det, i11 = (a * i9 - cc * g) / det, i12 = (cc * d - a * f) / det;
        float i20 = (d * h - e * g) / det, i21 = (b * g - a * h) / det, i22 = (a * e - b * d) / det;
        float W = (float)(*wid), H = (float)(*hgt);
        int kc = s_kc;
        if (t < kc) {
            int fidx = s_kidx[t];
            float val = s_kval[t];
            int bi = fidx / NCLS, cls = fidx - bi * NCLS;
            float4 bb = ((const float4*)bbox)[bi];
            float xs[4] = { bb.x, bb.z, bb.z, bb.x };
            float ys[4] = { bb.y, bb.y, bb.w, bb.w };
            float lox = 1e30f, loy = 1e30f, hix = -1e30f, hiy = -1e30f;
            #pragma unroll
            for (int q = 0; q < 4; ++q) {
                float X = i00 * xs[q] + i01 * ys[q] + i02;
                float Y = i10 * xs[q] + i11 * ys[q] + i12;
                float Z = i20 * xs[q] + i21 * ys[q] + i22;
                float px = X / Z, py = Y / Z;
                lox = fminf(lox, px); hix = fmaxf(hix, px);
                loy = fminf(loy, py); hiy = fmaxf(hiy, py);
            }
            out[t * 5 + 0] = fminf(fmaxf(lox, 0.f), W);
            out[t * 5 + 1] = fminf(fmaxf(loy, 0.f), H);
            out[t * 5 + 2] = fminf(fmaxf(hix, 0.f), W);
            out[t * 5 + 3] = fminf(fmaxf(hiy, 0.f), H);
            out[t * 5 + 4] = val;
            out[5 * NMSMAX + t] = (float)cls;
        } else {
            out[t * 5 + 0] = 0.f; out[t * 5 + 1] = 0.f; out[t * 5 + 2] = 0.f;
            out[t * 5 + 3] = 0.f; out[t * 5 + 4] = 0.f;
            out[5 * NMSMAX + t] = -1.0f;
        }
    }
}

extern "C" void kernel_launch(void* const* d_in, const int* in_sizes, int n_in,
                              void* d_out, int out_size, void* d_ws, size_t ws_size,
                              hipStream_t stream) {
    const float* preds = (const float*)d_in[0];
    const float* warp  = (const float*)d_in[2];
    const int*   hgt   = (const int*)d_in[3];
    const int*   wid   = (const int*)d_in[4];
    char* ws = (char*)d_ws;
    float*    bbox   = (float*)(ws + OFF_BBOX);
    uint32_t* part   = (uint32_t*)(ws + OFF_PART);
    uint32_t* scal   = (uint32_t*)(ws + OFF_SCAL);
    u64*      cand   = (u64*)(ws + OFF_CAND);
    u64*      sorted = (u64*)(ws + OFF_SORT);
    float*    outp   = (float*)d_out;

    void* args[] = { &preds, &bbox, &part, &scal, &cand, &sorted,
                     &warp, &hgt, &wid, &outp };
    hipLaunchCooperativeKernel((void*)k_all, dim3(GRID), dim3(256), args, 0, stream);
}

// Round 9
// 239.917 us; speedup vs baseline: 1.2850x; 1.2850x over previous
//
#include <hip/hip_runtime.h>
#include <stdint.h>

#define NPTS 21760
#define NCLS 80
#define NSC (NPTS * NCLS)          // 1,740,800 flat scores
#define PRE_K 4096
#define NMSMAX 100
#define CONF 0.35f
#define IOUT 0.6f
#define INSZ 1024.0f
#define CAND_CAP 8192
#define B_LO 16051u                 // __float_as_uint(0.35f) >> 16
#define B_HI 16224u                 // __float_as_uint(0.875f) >> 16 — hist floor
#define HB2 33                      // buckets 16224..16256 (sg==1.0f lands in 16256)
#define NBLK_F 340                  // k_fused blocks (NPTS*4/256)

// ---- workspace layout (bytes) ----
#define OFF_BBOX  0                                 // 21760 * float4 = 348,160
#define OFF_PART  (OFF_BBOX + NPTS * 16)            // 340 * 33 u32 partial hists
#define OFF_SCAL  (OFF_PART + NBLK_F * HB2 * 4)     // [1]=cand count
#define OFF_CAND  (OFF_SCAL + 64)                   // 8192 u64
#define OFF_SORT  (OFF_CAND + CAND_CAP * 8)         // 4096 u64
// total ~500 KB

typedef unsigned long long u64;

// fused: per-block (64 anchors) high-score partial histogram (plain stores — no
// pre-zero kernel needed) + bbox decode + sorted-prefill + scal zero. One preds pass.
__global__ __launch_bounds__(256) void k_fused(const float* __restrict__ preds,
                                               float* __restrict__ bbox,
                                               uint32_t* __restrict__ part,
                                               uint32_t* __restrict__ scal,
                                               u64* __restrict__ sorted) {
    __shared__ uint32_t lh[HB2];
    int t = threadIdx.x;
    int blk = blockIdx.x;
    if (t < HB2) lh[t] = 0;
    if (blk == 0 && t < 16) scal[t] = 0;
    if (blk < 16) sorted[blk * 256 + t] = ~0ull;   // 16*256 = PRE_K padding keys
    __syncthreads();

    // --- hist phase: 64 rows x 20 float4 of the 80-score region ---
    int n0 = blk * 64;
    #pragma unroll
    for (int q = 0; q < 5; ++q) {
        int idx = q * 256 + t;                   // 0..1279
        int a = idx / 20, f4 = idx - a * 20;
        float4 v = *(const float4*)(preds + (size_t)(n0 + a) * 112 + f4 * 4);
        float vv[4] = { v.x, v.y, v.z, v.w };
        #pragma unroll
        for (int e = 0; e < 4; ++e) {
            float sg = 1.0f / (1.0f + expf(-vv[e]));
            uint32_t b = __float_as_uint(sg) >> 16;
            if (b >= B_HI) atomicAdd(&lh[b - B_HI], 1u);
        }
    }
    __syncthreads();
    if (t < HB2) part[blk * HB2 + t] = lh[t];    // plain store: no pre-zero needed

    // --- bbox phase: 4 threads per anchor (one per distance k), shuffle-assemble ---
    int idx = blk * 256 + t;                     // 0 .. 87039
    int n = idx >> 2, k = idx & 3;
    int s, fs, local;
    if (n < 16384)      { s = 8;  fs = 128; local = n; }
    else if (n < 20480) { s = 16; fs = 64;  local = n - 16384; }
    else if (n < 21504) { s = 32; fs = 32;  local = n - 20480; }
    else                { s = 64; fs = 16;  local = n - 21504; }

    const float4* rp = (const float4*)(preds + (size_t)n * 112 + 80 + k * 8);
    float4 r0 = rp[0], r1 = rp[1];
    float r[8] = { r0.x, r0.y, r0.z, r0.w, r1.x, r1.y, r1.z, r1.w };
    float m = r[0];
    #pragma unroll
    for (int j = 1; j < 8; ++j) m = fmaxf(m, r[j]);
    float sum = 0.f, dot = 0.f;
    #pragma unroll
    for (int j = 0; j < 8; ++j) { float e = expf(r[j] - m); sum += e; dot += e * (float)j; }
    float dv = (dot / sum) * (float)s;

    int lane = t & 63, base = lane & ~3;
    float d0 = __shfl(dv, base + 0);
    float d1 = __shfl(dv, base + 1);
    float d2 = __shfl(dv, base + 2);
    float d3 = __shfl(dv, base + 3);
    if (k == 0) {
        float cx = (float)((local % fs) * s);
        float cy = (float)((local / fs) * s);
        float4 bb;
        bb.x = fminf(fmaxf(cx - d0, 0.f), INSZ);
        bb.y = fminf(fmaxf(cy - d1, 0.f), INSZ);
        bb.z = fminf(fmaxf(cx + d2, 0.f), INSZ);
        bb.w = fminf(fmaxf(cy + d3, 0.f), INSZ);
        ((float4*)bbox)[n] = bb;
    }
}

// compact with inlined cutoff: sum the 340x33 partial hists (L2-hot), thread 0
// walks the 33-bucket suffix from the top, then float4 recompute of sigmoid
// (bit-identical expression), LDS-buffered candidates, ONE global atomic per block.
__global__ __launch_bounds__(256) void k_compact(const float* __restrict__ preds,
                                                 const uint32_t* __restrict__ part,
                                                 uint32_t* __restrict__ scal,
                                                 u64* __restrict__ cand) {
    __shared__ uint32_t lh[HB2];
    __shared__ uint32_t cut_s;
    __shared__ u64 buf[4096];
    __shared__ uint32_t lcnt, lbase;
    int t = threadIdx.x;
    if (t < HB2) lh[t] = 0;
    if (t == 0) lcnt = 0;
    __syncthreads();
    for (int r = t; r < NBLK_F; r += 256) {      // sum partial rows
        const uint32_t* row = part + r * HB2;
        #pragma unroll
        for (int k = 0; k < HB2; ++k) {
            uint32_t v = row[k];
            if (v) atomicAdd(&lh[k], v);
        }
    }
    __syncthreads();
    if (t == 0) {
        uint32_t suf = 0, c = B_LO;              // fallback: take all > CONF
        for (int b = HB2 - 1; b >= 0; --b) {
            suf += lh[b];
            if (suf >= PRE_K) { c = B_HI + (uint32_t)b; break; }
        }
        cut_s = c;
    }
    __syncthreads();
    uint32_t cut = cut_s;

    // 425 blocks x 1024 float4 = 435,200 float4 = NSC floats exactly
    #pragma unroll
    for (int q = 0; q < 4; ++q) {
        int g = blockIdx.x * 1024 + q * 256 + t;
        int a = g / 20, c4 = g - a * 20;
        float4 v = *(const float4*)(preds + (size_t)a * 112 + c4 * 4);
        float vv[4] = { v.x, v.y, v.z, v.w };
        #pragma unroll
        for (int e = 0; e < 4; ++e) {
            float sg = 1.0f / (1.0f + expf(-vv[e]));   // byte-identical to hist phase
            uint32_t bits = __float_as_uint(sg);
            if ((bits >> 16) >= cut) {
                uint32_t p = atomicAdd(&lcnt, 1u);
                if (p < 4096u) buf[p] = ((u64)(~bits) << 32) | (u64)(uint32_t)(a * 80 + c4 * 4 + e);
            }
        }
    }
    __syncthreads();
    uint32_t cnt = lcnt < 4096u ? lcnt : 4096u;
    if (t == 0) lbase = atomicAdd(&scal[1], cnt);
    __syncthreads();
    uint32_t b0 = lbase;
    for (uint32_t k = t; k < cnt; k += 256) {
        uint32_t pos = b0 + k;
        if (pos < CAND_CAP) cand[pos] = buf[k];
    }
}

// rank-by-count, 8 threads per candidate: sorted position == #smaller keys.
__global__ __launch_bounds__(256) void k_rank(const uint32_t* __restrict__ scal,
                                              const u64* __restrict__ cand,
                                              u64* __restrict__ sorted) {
    __shared__ u64 tile[256];
    int t = threadIdx.x;
    int c = t >> 3;                 // candidate-in-block 0..31
    int s = t & 7;                  // j-subgroup 0..7
    int i = blockIdx.x * 32 + c;
    uint32_t M = scal[1];
    if (M > CAND_CAP) M = CAND_CAP;
    u64 my = (i < (int)M) ? cand[i] : ~0ull;
    int rank = 0;
    uint32_t ntiles = (M + 255u) >> 8;
    for (uint32_t tb = 0; tb < ntiles; ++tb) {
        uint32_t j = tb * 256 + t;
        tile[t] = (j < M) ? cand[j] : ~0ull;     // pad keys never count as smaller
        __syncthreads();
        #pragma unroll 8
        for (int it = 0; it < 32; ++it)
            rank += (int)(tile[it * 8 + s] < my);
        __syncthreads();
    }
    rank += __shfl_down(rank, 4, 8);
    rank += __shfl_down(rank, 2, 8);
    rank += __shfl_down(rank, 1, 8);
    if (s == 0 && i < (int)M && rank < PRE_K) sorted[rank] = my;
}

__device__ inline bool iou_gt(const float* a, const float* b) {
    float aa = (a[2] - a[0]) * (a[3] - a[1]);
    float ab = (b[2] - b[0]) * (b[3] - b[1]);
    float lx = fmaxf(a[0], b[0]), ly = fmaxf(a[1], b[1]);
    float rx = fminf(a[2], b[2]), ry = fminf(a[3], b[3]);
    float w = fmaxf(rx - lx, 0.f), h = fmaxf(ry - ly, 0.f);
    float inter = w * h;
    return inter / (aa + ab - inter + 1e-6f) > IOUT;
}

// streaming greedy NMS with early-stop at 100 kept, then inverse-warp epilogue
__global__ __launch_bounds__(256) void k_nms(const float* __restrict__ bbox,
                                             const u64* __restrict__ sorted,
                                             const float* __restrict__ warp,
                                             const int* __restrict__ hgt,
                                             const int* __restrict__ wid,
                                             float* __restrict__ out) {
    __shared__ float s_cbox[64][4];
    __shared__ float s_cval[64];
    __shared__ int   s_cidx[64];
    __shared__ u64   s_intra[64];
    __shared__ int   s_sup[64];
    __shared__ int   s_kidx[NMSMAX];
    __shared__ float s_kval[NMSMAX];
    __shared__ float s_kbox[NMSMAX][4];
    __shared__ int   s_kc, s_done;
    int tid = threadIdx.x;
    if (tid == 0) { s_kc = 0; s_done = 0; }
    __syncthreads();

    for (int c = 0; c < PRE_K / 64; ++c) {
        if (tid < 64) {
            u64 sk = sorted[c * 64 + tid];
            uint32_t fidx = (uint32_t)sk;
            float val = __uint_as_float(~(uint32_t)(sk >> 32));
            uint32_t bi = fidx / NCLS;
            if (bi >= NPTS) bi = NPTS - 1;       // padding keys: clamp (invalid anyway)
            int cls = (int)fidx - (int)bi * NCLS;
            float off = (float)cls * (INSZ + 1.0f);
            float4 bb = ((const float4*)bbox)[bi];
            s_cbox[tid][0] = bb.x + off; s_cbox[tid][1] = bb.y + off;
            s_cbox[tid][2] = bb.z + off; s_cbox[tid][3] = bb.w + off;
            s_cval[tid] = val; s_cidx[tid] = (int)fidx; s_sup[tid] = 0;
        }
        __syncthreads();
        int kc_snap = s_kc;
        {   // suppression by previously-kept boxes (256 threads = 64 cands x 4 groups)
            int j = tid & 63, g = tid >> 6;
            bool sup = false;
            for (int k = g; k < kc_snap; k += 4)
                sup |= iou_gt(s_cbox[j], s_kbox[k]);
            if (sup) atomicOr(&s_sup[j], 1);
        }
        if (tid < 64) {  // intra-chunk upper-triangular mask
            u64 rowm = 0;
            for (int j2 = tid + 1; j2 < 64; ++j2)
                if (iou_gt(s_cbox[tid], s_cbox[j2])) rowm |= 1ull << j2;
            s_intra[tid] = rowm;
        }
        __syncthreads();
        if (tid < 64) {  // serial resolve, wave 0 only, wave-uniform control
            u64 intrarow = s_intra[tid];
            u64 supw = __ballot(s_sup[tid] != 0);
            u64 valw = __ballot(s_cval[tid] > CONF);
            u64 cur = valw & ~supw;
            int kc = kc_snap;
            for (int b = 0; b < 64; ++b) {
                if (kc >= NMSMAX) break;
                if ((cur >> b) & 1ull) {
                    if (tid == 0) { s_kidx[kc] = s_cidx[b]; s_kval[kc] = s_cval[b]; }
                    if (tid < 4) s_kbox[kc][tid] = s_cbox[b][tid];
                    kc++;
                    cur &= ~__shfl(intrarow, b);
                }
            }
            if (tid == 0) { s_kc = kc; s_done = (kc >= NMSMAX) ? 1 : 0; }
        }
        __syncthreads();
        if (s_done) break;
    }
    __syncthreads();

    // epilogue: inverse warp, clip, write dets (100x5) then labels (100)
    if (tid < NMSMAX) {
        float a = warp[0], b = warp[1], cc = warp[2];
        float d = warp[3], e = warp[4], f = warp[5];
        float g = warp[6], h = warp[7], i9 = warp[8];
        float det = a * (e * i9 - f * h) - b * (d * i9 - f * g) + cc * (d * h - e * g);
        float i00 = (e * i9 - f * h) / det, i01 = (cc * h - b * i9) / det, i02 = (b * f - cc * e) / det;
        float i10 = (f * g - d * i9) / det, i11 = (a * i9 - cc * g) / det, i12 = (cc * d - a * f) / det;
        float i20 = (d * h - e * g) / det, i21 = (b * g - a * h) / det, i22 = (a * e - b * d) / det;
        float W = (float)(*wid), H = (float)(*hgt);
        int kc = s_kc;
        if (tid < kc) {
            int fidx = s_kidx[tid];
            float val = s_kval[tid];
            int bi = fidx / NCLS, cls = fidx - bi * NCLS;
            float4 bb = ((const float4*)bbox)[bi];
            float xs[4] = { bb.x, bb.z, bb.z, bb.x };
            float ys[4] = { bb.y, bb.y, bb.w, bb.w };
            float lox = 1e30f, loy = 1e30f, hix = -1e30f, hiy = -1e30f;
            #pragma unroll
            for (int q = 0; q < 4; ++q) {
                float X = i00 * xs[q] + i01 * ys[q] + i02;
                float Y = i10 * xs[q] + i11 * ys[q] + i12;
                float Z = i20 * xs[q] + i21 * ys[q] + i22;
                float px = X / Z, py = Y / Z;
                lox = fminf(lox, px); hix = fmaxf(hix, px);
                loy = fminf(loy, py); hiy = fmaxf(hiy, py);
            }
            out[tid * 5 + 0] = fminf(fmaxf(lox, 0.f), W);
            out[tid * 5 + 1] = fminf(fmaxf(loy, 0.f), H);
            out[tid * 5 + 2] = fminf(fmaxf(hix, 0.f), W);
            out[tid * 5 + 3] = fminf(fmaxf(hiy, 0.f), H);
            out[tid * 5 + 4] = val;
            out[5 * NMSMAX + tid] = (float)cls;
        } else {
            out[tid * 5 + 0] = 0.f; out[tid * 5 + 1] = 0.f; out[tid * 5 + 2] = 0.f;
            out[tid * 5 + 3] = 0.f; out[tid * 5 + 4] = 0.f;
            out[5 * NMSMAX + tid] = -1.0f;
        }
    }
}

extern "C" void kernel_launch(void* const* d_in, const int* in_sizes, int n_in,
                              void* d_out, int out_size, void* d_ws, size_t ws_size,
                              hipStream_t stream) {
    const float* preds = (const float*)d_in[0];
    const float* warp  = (const float*)d_in[2];
    const int*   hgt   = (const int*)d_in[3];
    const int*   wid   = (const int*)d_in[4];
    char* ws = (char*)d_ws;
    float*    bbox   = (float*)(ws + OFF_BBOX);
    uint32_t* part   = (uint32_t*)(ws + OFF_PART);
    uint32_t* scal   = (uint32_t*)(ws + OFF_SCAL);
    u64*      cand   = (u64*)(ws + OFF_CAND);
    u64*      sorted = (u64*)(ws + OFF_SORT);

    hipLaunchKernelGGL(k_fused,   dim3(NBLK_F), dim3(256), 0, stream, preds, bbox, part, scal, sorted);
    hipLaunchKernelGGL(k_compact, dim3(NSC / 4096), dim3(256), 0, stream, preds, part, scal, cand);
    hipLaunchKernelGGL(k_rank,    dim3(CAND_CAP / 32), dim3(256), 0, stream, scal, cand, sorted);
    hipLaunchKernelGGL(k_nms,     dim3(1), dim3(256), 0, stream, bbox, sorted, warp, hgt, wid, (float*)d_out);
}

// Round 11
// 151.275 us; speedup vs baseline: 2.0379x; 1.5860x over previous
//
#include <hip/hip_runtime.h>
#include <stdint.h>

#define NPTS 21760
#define NCLS 80
#define NSC (NPTS * NCLS)          // 1,740,800 flat scores
#define PRE_K 4096
#define NMSMAX 100
#define CONF 0.35f
#define IOUT 0.6f
#define INSZ 1024.0f
#define CAND_CAP 8192
#define B_LO 16051u                 // __float_as_uint(0.35f) >> 16
#define B_HI 16224u                 // __float_as_uint(0.875f) >> 16 — hist floor
#define HB2 33                      // buckets 16224..16256 (sg==1.0f lands in 16256)
#define NBLK_F 340                  // k_fused blocks (NPTS*4/256)

// ---- workspace layout (bytes) ----
#define OFF_BBOX  0                                 // 21760 * float4 = 348,160
#define OFF_PART  (OFF_BBOX + NPTS * 16)            // 340 * 33 u32 partial hists
#define OFF_SCAL  (OFF_PART + NBLK_F * HB2 * 4)     // [1]=cand count
#define OFF_CAND  (OFF_SCAL + 64)                   // 8192 u64
#define OFF_SORT  (OFF_CAND + CAND_CAP * 8)         // 4096 u64
// total ~500 KB

typedef unsigned long long u64;

// fused: per-block (64 anchors) high-score partial histogram (plain stores — no
// pre-zero kernel needed) + bbox decode + sorted-prefill + scal zero. One preds pass.
__global__ __launch_bounds__(256) void k_fused(const float* __restrict__ preds,
                                               float* __restrict__ bbox,
                                               uint32_t* __restrict__ part,
                                               uint32_t* __restrict__ scal,
                                               u64* __restrict__ sorted) {
    __shared__ uint32_t lh[HB2];
    int t = threadIdx.x;
    int blk = blockIdx.x;
    if (t < HB2) lh[t] = 0;
    if (blk == 0 && t < 16) scal[t] = 0;
    if (blk < 16) sorted[blk * 256 + t] = ~0ull;   // 16*256 = PRE_K padding keys
    __syncthreads();

    // --- hist phase: 64 rows x 20 float4 of the 80-score region ---
    int n0 = blk * 64;
    #pragma unroll
    for (int q = 0; q < 5; ++q) {
        int idx = q * 256 + t;                   // 0..1279
        int a = idx / 20, f4 = idx - a * 20;
        float4 v = *(const float4*)(preds + (size_t)(n0 + a) * 112 + f4 * 4);
        float vv[4] = { v.x, v.y, v.z, v.w };
        #pragma unroll
        for (int e = 0; e < 4; ++e) {
            float sg = 1.0f / (1.0f + expf(-vv[e]));
            uint32_t b = __float_as_uint(sg) >> 16;
            if (b >= B_HI) atomicAdd(&lh[b - B_HI], 1u);
        }
    }
    __syncthreads();
    if (t < HB2) part[blk * HB2 + t] = lh[t];    // plain store: no pre-zero needed

    // --- bbox phase: 4 threads per anchor (one per distance k), shuffle-assemble ---
    int idx = blk * 256 + t;                     // 0 .. 87039
    int n = idx >> 2, k = idx & 3;
    int s, fs, local;
    if (n < 16384)      { s = 8;  fs = 128; local = n; }
    else if (n < 20480) { s = 16; fs = 64;  local = n - 16384; }
    else if (n < 21504) { s = 32; fs = 32;  local = n - 20480; }
    else                { s = 64; fs = 16;  local = n - 21504; }

    const float4* rp = (const float4*)(preds + (size_t)n * 112 + 80 + k * 8);
    float4 r0 = rp[0], r1 = rp[1];
    float r[8] = { r0.x, r0.y, r0.z, r0.w, r1.x, r1.y, r1.z, r1.w };
    float m = r[0];
    #pragma unroll
    for (int j = 1; j < 8; ++j) m = fmaxf(m, r[j]);
    float sum = 0.f, dot = 0.f;
    #pragma unroll
    for (int j = 0; j < 8; ++j) { float e = expf(r[j] - m); sum += e; dot += e * (float)j; }
    float dv = (dot / sum) * (float)s;

    int lane = t & 63, base = lane & ~3;
    float d0 = __shfl(dv, base + 0);
    float d1 = __shfl(dv, base + 1);
    float d2 = __shfl(dv, base + 2);
    float d3 = __shfl(dv, base + 3);
    if (k == 0) {
        float cx = (float)((local % fs) * s);
        float cy = (float)((local / fs) * s);
        float4 bb;
        bb.x = fminf(fmaxf(cx - d0, 0.f), INSZ);
        bb.y = fminf(fmaxf(cy - d1, 0.f), INSZ);
        bb.z = fminf(fmaxf(cx + d2, 0.f), INSZ);
        bb.w = fminf(fmaxf(cy + d3, 0.f), INSZ);
        ((float4*)bbox)[n] = bb;
    }
}

// compact with inlined cutoff: transposed ATOMIC-FREE partial-hist reduction
// (264 work items looped over 256 threads — R10 bug was `if (t<264)` with a
// 256-thread block leaving lh8[7][25..32] uninitialized), thread 0 walks the
// 33-bucket suffix, then float4 recompute of sigmoid (bit-identical
// expression), LDS-buffered candidates, ONE global atomic per block.
__global__ __launch_bounds__(256) void k_compact(const float* __restrict__ preds,
                                                 const uint32_t* __restrict__ part,
                                                 uint32_t* __restrict__ scal,
                                                 u64* __restrict__ cand) {
    __shared__ uint32_t lh8[8][HB2 + 1];         // +1 pad: stride 34 banks
    __shared__ uint32_t cut_s;
    __shared__ u64 buf[4096];
    __shared__ uint32_t lcnt, lbase;
    int t = threadIdx.x;
    if (t == 0) lcnt = 0;
    // transposed sum: work item (c,b) sums bucket b over rows [c*43, c*43+43)
    for (int w = t; w < 8 * HB2; w += 256) {     // 264 items over 256 threads
        int c = w / HB2, b = w - c * HB2;        // c 0..7, b 0..32
        int r0 = c * 43;
        int r1 = r0 + 43; if (r1 > NBLK_F) r1 = NBLK_F;
        uint32_t sum = 0;
        for (int r = r0; r < r1; ++r) sum += part[r * HB2 + b];
        lh8[c][b] = sum;
    }
    __syncthreads();
    if (t == 0) {
        uint32_t suf = 0, c = B_LO;              // fallback: take all > CONF
        for (int b = HB2 - 1; b >= 0; --b) {
            uint32_t tot = 0;
            #pragma unroll
            for (int cc = 0; cc < 8; ++cc) tot += lh8[cc][b];
            suf += tot;
            if (suf >= PRE_K) { c = B_HI + (uint32_t)b; break; }
        }
        cut_s = c;
    }
    __syncthreads();
    uint32_t cut = cut_s;

    // 425 blocks x 1024 float4 = 435,200 float4 = NSC floats exactly
    #pragma unroll
    for (int q = 0; q < 4; ++q) {
        int g = blockIdx.x * 1024 + q * 256 + t;
        int a = g / 20, c4 = g - a * 20;
        float4 v = *(const float4*)(preds + (size_t)a * 112 + c4 * 4);
        float vv[4] = { v.x, v.y, v.z, v.w };
        #pragma unroll
        for (int e = 0; e < 4; ++e) {
            float sg = 1.0f / (1.0f + expf(-vv[e]));   // byte-identical to hist phase
            uint32_t bits = __float_as_uint(sg);
            if ((bits >> 16) >= cut) {
                uint32_t p = atomicAdd(&lcnt, 1u);
                if (p < 4096u) buf[p] = ((u64)(~bits) << 32) | (u64)(uint32_t)(a * 80 + c4 * 4 + e);
            }
        }
    }
    __syncthreads();
    uint32_t cnt = lcnt < 4096u ? lcnt : 4096u;
    if (t == 0) lbase = atomicAdd(&scal[1], cnt);
    __syncthreads();
    uint32_t b0 = lbase;
    for (uint32_t k = t; k < cnt; k += 256) {
        uint32_t pos = b0 + k;
        if (pos < CAND_CAP) cand[pos] = buf[k];
    }
}

// rank-by-count, 8 threads per candidate: sorted position == #smaller keys.
__global__ __launch_bounds__(256) void k_rank(const uint32_t* __restrict__ scal,
                                              const u64* __restrict__ cand,
                                              u64* __restrict__ sorted) {
    __shared__ u64 tile[256];
    int t = threadIdx.x;
    int c = t >> 3;                 // candidate-in-block 0..31
    int s = t & 7;                  // j-subgroup 0..7
    int i = blockIdx.x * 32 + c;
    uint32_t M = scal[1];
    if (M > CAND_CAP) M = CAND_CAP;
    u64 my = (i < (int)M) ? cand[i] : ~0ull;
    int rank = 0;
    uint32_t ntiles = (M + 255u) >> 8;
    for (uint32_t tb = 0; tb < ntiles; ++tb) {
        uint32_t j = tb * 256 + t;
        tile[t] = (j < M) ? cand[j] : ~0ull;     // pad keys never count as smaller
        __syncthreads();
        #pragma unroll 8
        for (int it = 0; it < 32; ++it)
            rank += (int)(tile[it * 8 + s] < my);
        __syncthreads();
    }
    rank += __shfl_down(rank, 4, 8);
    rank += __shfl_down(rank, 2, 8);
    rank += __shfl_down(rank, 1, 8);
    if (s == 0 && i < (int)M && rank < PRE_K) sorted[rank] = my;
}

__device__ inline bool iou_gt(const float* a, const float* b) {
    float aa = (a[2] - a[0]) * (a[3] - a[1]);
    float ab = (b[2] - b[0]) * (b[3] - b[1]);
    float lx = fmaxf(a[0], b[0]), ly = fmaxf(a[1], b[1]);
    float rx = fminf(a[2], b[2]), ry = fminf(a[3], b[3]);
    float w = fmaxf(rx - lx, 0.f), h = fmaxf(ry - ly, 0.f);
    float inter = w * h;
    return inter / (aa + ab - inter + 1e-6f) > IOUT;
}

// streaming greedy NMS with early-stop at 100 kept, then inverse-warp epilogue
__global__ __launch_bounds__(256) void k_nms(const float* __restrict__ bbox,
                                             const u64* __restrict__ sorted,
                                             const float* __restrict__ warp,
                                             const int* __restrict__ hgt,
                                             const int* __restrict__ wid,
                                             float* __restrict__ out) {
    __shared__ float s_cbox[64][4];
    __shared__ float s_cval[64];
    __shared__ int   s_cidx[64];
    __shared__ u64   s_intra[64];
    __shared__ int   s_sup[64];
    __shared__ int   s_kidx[NMSMAX];
    __shared__ float s_kval[NMSMAX];
    __shared__ float s_kbox[NMSMAX][4];
    __shared__ int   s_kc, s_done;
    int tid = threadIdx.x;
    if (tid == 0) { s_kc = 0; s_done = 0; }
    __syncthreads();

    for (int c = 0; c < PRE_K / 64; ++c) {
        if (tid < 64) {
            u64 sk = sorted[c * 64 + tid];
            uint32_t fidx = (uint32_t)sk;
            float val = __uint_as_float(~(uint32_t)(sk >> 32));
            uint32_t bi = fidx / NCLS;
            if (bi >= NPTS) bi = NPTS - 1;       // padding keys: clamp (invalid anyway)
            int cls = (int)fidx - (int)bi * NCLS;
            float off = (float)cls * (INSZ + 1.0f);
            float4 bb = ((const float4*)bbox)[bi];
            s_cbox[tid][0] = bb.x + off; s_cbox[tid][1] = bb.y + off;
            s_cbox[tid][2] = bb.z + off; s_cbox[tid][3] = bb.w + off;
            s_cval[tid] = val; s_cidx[tid] = (int)fidx; s_sup[tid] = 0;
        }
        __syncthreads();
        int kc_snap = s_kc;
        {   // suppression by previously-kept boxes (256 threads = 64 cands x 4 groups)
            int j = tid & 63, g = tid >> 6;
            bool sup = false;
            for (int k = g; k < kc_snap; k += 4)
                sup |= iou_gt(s_cbox[j], s_kbox[k]);
            if (sup) atomicOr(&s_sup[j], 1);
        }
        if (tid < 64) {  // intra-chunk upper-triangular mask
            u64 rowm = 0;
            for (int j2 = tid + 1; j2 < 64; ++j2)
                if (iou_gt(s_cbox[tid], s_cbox[j2])) rowm |= 1ull << j2;
            s_intra[tid] = rowm;
        }
        __syncthreads();
        if (tid < 64) {  // serial resolve, wave 0 only, wave-uniform control
            u64 intrarow = s_intra[tid];
            u64 supw = __ballot(s_sup[tid] != 0);
            u64 valw = __ballot(s_cval[tid] > CONF);
            u64 cur = valw & ~supw;
            int kc = kc_snap;
            for (int b = 0; b < 64; ++b) {
                if (kc >= NMSMAX) break;
                if ((cur >> b) & 1ull) {
                    if (tid == 0) { s_kidx[kc] = s_cidx[b]; s_kval[kc] = s_cval[b]; }
                    if (tid < 4) s_kbox[kc][tid] = s_cbox[b][tid];
                    kc++;
                    cur &= ~__shfl(intrarow, b);
                }
            }
            if (tid == 0) { s_kc = kc; s_done = (kc >= NMSMAX) ? 1 : 0; }
        }
        __syncthreads();
        if (s_done) break;
    }
    __syncthreads();

    // epilogue: inverse warp, clip, write dets (100x5) then labels (100)
    if (tid < NMSMAX) {
        float a = warp[0], b = warp[1], cc = warp[2];
        float d = warp[3], e = warp[4], f = warp[5];
        float g = warp[6], h = warp[7], i9 = warp[8];
        float det = a * (e * i9 - f * h) - b * (d * i9 - f * g) + cc * (d * h - e * g);
        float i00 = (e * i9 - f * h) / det, i01 = (cc * h - b * i9) / det, i02 = (b * f - cc * e) / det;
        float i10 = (f * g - d * i9) / det, i11 = (a * i9 - cc * g) / det, i12 = (cc * d - a * f) / det;
        float i20 = (d * h - e * g) / det, i21 = (b * g - a * h) / det, i22 = (a * e - b * d) / det;
        float W = (float)(*wid), H = (float)(*hgt);
        int kc = s_kc;
        if (tid < kc) {
            int fidx = s_kidx[tid];
            float val = s_kval[tid];
            int bi = fidx / NCLS, cls = fidx - bi * NCLS;
            float4 bb = ((const float4*)bbox)[bi];
            float xs[4] = { bb.x, bb.z, bb.z, bb.x };
            float ys[4] = { bb.y, bb.y, bb.w, bb.w };
            float lox = 1e30f, loy = 1e30f, hix = -1e30f, hiy = -1e30f;
            #pragma unroll
            for (int q = 0; q < 4; ++q) {
                float X = i00 * xs[q] + i01 * ys[q] + i02;
                float Y = i10 * xs[q] + i11 * ys[q] + i12;
                float Z = i20 * xs[q] + i21 * ys[q] + i22;
                float px = X / Z, py = Y / Z;
                lox = fminf(lox, px); hix = fmaxf(hix, px);
                loy = fminf(loy, py); hiy = fmaxf(hiy, py);
            }
            out[tid * 5 + 0] = fminf(fmaxf(lox, 0.f), W);
            out[tid * 5 + 1] = fminf(fmaxf(loy, 0.f), H);
            out[tid * 5 + 2] = fminf(fmaxf(hix, 0.f), W);
            out[tid * 5 + 3] = fminf(fmaxf(hiy, 0.f), H);
            out[tid * 5 + 4] = val;
            out[5 * NMSMAX + tid] = (float)cls;
        } else {
            out[tid * 5 + 0] = 0.f; out[tid * 5 + 1] = 0.f; out[tid * 5 + 2] = 0.f;
            out[tid * 5 + 3] = 0.f; out[tid * 5 + 4] = 0.f;
            out[5 * NMSMAX + tid] = -1.0f;
        }
    }
}

extern "C" void kernel_launch(void* const* d_in, const int* in_sizes, int n_in,
                              void* d_out, int out_size, void* d_ws, size_t ws_size,
                              hipStream_t stream) {
    const float* preds = (const float*)d_in[0];
    const float* warp  = (const float*)d_in[2];
    const int*   hgt   = (const int*)d_in[3];
    const int*   wid   = (const int*)d_in[4];
    char* ws = (char*)d_ws;
    float*    bbox   = (float*)(ws + OFF_BBOX);
    uint32_t* part   = (uint32_t*)(ws + OFF_PART);
    uint32_t* scal   = (uint32_t*)(ws + OFF_SCAL);
    u64*      cand   = (u64*)(ws + OFF_CAND);
    u64*      sorted = (u64*)(ws + OFF_SORT);

    hipLaunchKernelGGL(k_fused,   dim3(NBLK_F), dim3(256), 0, stream, preds, bbox, part, scal, sorted);
    hipLaunchKernelGGL(k_compact, dim3(NSC / 4096), dim3(256), 0, stream, preds, part, scal, cand);
    hipLaunchKernelGGL(k_rank,    dim3(CAND_CAP / 32), dim3(256), 0, stream, scal, cand, sorted);
    hipLaunchKernelGGL(k_nms,     dim3(1), dim3(256), 0, stream, bbox, sorted, warp, hgt, wid, (float*)d_out);
}